// Round 8
// baseline (324.073 us; speedup 1.0000x reference)
//
#include <hip/hip_runtime.h>

// AttentionLayer: N=8, L=1024, D_MODEL=1024, H=16, d_head=64.
// out  = softmax(QK^T/8)V reshaped   (8,1024,1024) fp32
// attn = mean over heads of softmax  (8,1024,1024) fp32, after out.
//
// R10-R13: k2 plateau 180us (latency-bound; prefetch/traffic/LDS attacks
//      null). total-k2 = ~70us invariant under k0 rewrite -> k0 not the gap.
// R14: SPLIT k2 for diagnosis + exploitation.
//      k2a = loop1 + out + ir-store (no LDS at all).
//      k3  = attn mean, restructured: wave owns (16q x 64s) strip, heads in
//            OUTER loop, fp32 register accumulation of ir_h*exp2(QK*CE).
//            Zero LDS, zero barriers, no bf16 rounding of attn.
//            launch_bounds(512,8): <=64 VGPR -> 4 blocks/CU (full occ).
//      ws 32.5 MB (bKw + bTw + ir); ws_size-checked fallback = monolithic.

#define NB 8
#define LQ 1024
#define DM 1024
#define NH 16
#define DH 64
#define AW 68           // attn stage row stride (shorts), fallback kernel
#define TR 528          // k0 LDS row stride (shorts)

typedef __attribute__((ext_vector_type(4))) float f32x4;
typedef __attribute__((ext_vector_type(8))) short bf16x8;
typedef __attribute__((ext_vector_type(4))) short bf16x4;
typedef __attribute__((ext_vector_type(4))) int   i32x4;
typedef __attribute__((ext_vector_type(2))) int   i32x2;

__device__ inline short f2bf(float f){
  unsigned u = __builtin_bit_cast(unsigned, f);
  u += 0x7fffu + ((u >> 16) & 1u);   // RNE (inputs finite)
  return (short)(u >> 16);
}
__device__ inline float bf2f(short s){
  unsigned u = ((unsigned)(unsigned short)s) << 16;
  return __builtin_bit_cast(float, u);
}
__device__ inline int cvt_pk_bf16(float lo, float hi){
  int r;
  asm("v_cvt_pk_bf16_f32 %0, %1, %2" : "=v"(r) : "v"(lo), "v"(hi));
  return r;
}

// ---------------- k0: fp32 -> bf16, coalesced writes (R13) ------------------
__global__ __launch_bounds__(256) void k0_convert(const float* __restrict__ in,
                                                  short* __restrict__ bKw,
                                                  short* __restrict__ bTw){
  __shared__ short T[32*TR];
  int b   = blockIdx.x;
  int dh  = b & 1;
  int win = (b >> 1) & 31;
  int n   = b >> 6;
  int tid = threadIdx.x;
  int w    = tid >> 6;
  int lane = tid & 63;

  {
    int s  = tid >> 3;
    int c0 = (tid & 7) << 2;
    const float* src = in + ((size_t)(n*LQ + win*32 + s))*DM + dh*512;
    #pragma unroll
    for (int p = 0; p < 16; ++p){
      int c = p*32 + c0;
      f32x4 f = *(const f32x4*)(src + c);
      bf16x4 v = {f2bf(f.x), f2bf(f.y), f2bf(f.z), f2bf(f.w)};
      *(bf16x4*)&T[s*TR + c] = v;
    }
  }
  __syncthreads();

  {
    int r8 = lane >> 3;
    int cc = (lane & 7) << 3;
    #pragma unroll
    for (int pass = 0; pass < 8; ++pass){
      int t  = pass*4 + w;
      int hl = t >> 2;
      int rg = t & 3;
      int s  = rg*8 + r8;
      bf16x8 v = *(const bf16x8*)&T[s*TR + hl*64 + cc];
      int h = dh*8 + hl;
      size_t dst = ((size_t)((n*NH + h)*LQ + win*32 + s))*DH + cc;
      *(bf16x8*)(bKw + dst) = v;
    }
  }

  {
    #pragma unroll
    for (int pass = 0; pass < 8; ++pass){
      int t    = pass*4 + w;
      int dloc = t*16 + (lane >> 2);
      int sl8  = (lane & 3) << 3;
      short t0 = T[(sl8+0)*TR + dloc];
      short t1 = T[(sl8+1)*TR + dloc];
      short t2 = T[(sl8+2)*TR + dloc];
      short t3 = T[(sl8+3)*TR + dloc];
      short t4 = T[(sl8+4)*TR + dloc];
      short t5 = T[(sl8+5)*TR + dloc];
      short t6 = T[(sl8+6)*TR + dloc];
      short t7 = T[(sl8+7)*TR + dloc];
      bf16x8 v = {t0, t1, t2, t3, t4, t5, t6, t7};
      int d = dh*512 + dloc;
      size_t dst = ((size_t)((n*32 + win)*DM + d))*32 + sl8;
      *(bf16x8*)(bTw + dst) = v;
    }
  }
}

// ---------------- k2a: loop1 only (R10 datapath) + ir store -----------------
__global__ __launch_bounds__(1024, 4) void k2a_fwd(const short* __restrict__ bKw,
                                                   const short* __restrict__ bTw,
                                                   float* __restrict__ out,
                                                   float* __restrict__ irw){
  int tid  = threadIdx.x;
  int lane = tid & 63;
  int w    = tid >> 6;                  // wave id == head id
  int l16  = lane & 15;
  int quad = lane >> 4;
  int n  = blockIdx.x & 7;              // XCD swizzle
  int q0 = (blockIdx.x >> 3) << 5;      // 32 q-rows per block

  const float CE = 0.1803368801111244f; // 0.125 * log2(e)
  const f32x4 vzero = {0.f, 0.f, 0.f, 0.f};

  size_t hb = ((size_t)(n*NH + w))*LQ*DH;
  const short* kb  = bKw + hb + (size_t)l16*DH + quad*8;
  const short* kbp = bKw + hb + (size_t)((l16 >> 2)*8 + (l16 & 3))*DH + quad*8;

  bf16x8 qfA0 = *(const bf16x8*)(kb + (size_t)q0*DH);
  bf16x8 qfA1 = *(const bf16x8*)(kb + (size_t)q0*DH + 32);
  bf16x8 qfB0 = *(const bf16x8*)(kb + (size_t)(q0+16)*DH);
  bf16x8 qfB1 = *(const bf16x8*)(kb + (size_t)(q0+16)*DH + 32);

  f32x4 oaccA[4], oaccB[4];
  #pragma unroll
  for (int dt = 0; dt < 4; ++dt){ oaccA[dt] = vzero; oaccB[dt] = vzero; }
  float rsumA = 0.f, rsumB = 0.f;

  bf16x8 kf0 = *(const bf16x8*)kbp;
  bf16x8 kf1 = *(const bf16x8*)(kbp + 32);
  bf16x8 vpre[4];
  int paA0 = 0, paA1 = 0, paB0 = 0, paB1 = 0;
  for (int f = 0; f < 64; ++f){
    int fn = (f + 1) & 63;
    int tn = (fn >> 1)*32 + (fn & 1)*4;
    const short* nkp = kbp + (size_t)tn*DH;
    bf16x8 nkf0 = *(const bf16x8*)nkp;
    bf16x8 nkf1 = *(const bf16x8*)(nkp + 32);
    if ((f & 1) == 0){
      int vwin = f >> 1;
      #pragma unroll
      for (int dt = 0; dt < 4; ++dt){
        const short* vp = bTw + ((size_t)((n*32 + vwin)*DM + w*DH + dt*16 + l16))*32 + quad*8;
        vpre[dt] = *(const bf16x8*)vp;
      }
    }
    f32x4 stA = vzero, stB = vzero;
    stA = __builtin_amdgcn_mfma_f32_16x16x32_bf16(kf0, qfA0, stA, 0, 0, 0);
    stA = __builtin_amdgcn_mfma_f32_16x16x32_bf16(kf1, qfA1, stA, 0, 0, 0);
    stB = __builtin_amdgcn_mfma_f32_16x16x32_bf16(kf0, qfB0, stB, 0, 0, 0);
    stB = __builtin_amdgcn_mfma_f32_16x16x32_bf16(kf1, qfB1, stB, 0, 0, 0);
    float eA0 = __builtin_amdgcn_exp2f(stA[0]*CE);
    float eA1 = __builtin_amdgcn_exp2f(stA[1]*CE);
    float eA2 = __builtin_amdgcn_exp2f(stA[2]*CE);
    float eA3 = __builtin_amdgcn_exp2f(stA[3]*CE);
    float eB0 = __builtin_amdgcn_exp2f(stB[0]*CE);
    float eB1 = __builtin_amdgcn_exp2f(stB[1]*CE);
    float eB2 = __builtin_amdgcn_exp2f(stB[2]*CE);
    float eB3 = __builtin_amdgcn_exp2f(stB[3]*CE);
    rsumA += (eA0 + eA1) + (eA2 + eA3);
    rsumB += (eB0 + eB1) + (eB2 + eB3);
    int dA0 = cvt_pk_bf16(eA0, eA1), dA1 = cvt_pk_bf16(eA2, eA3);
    int dB0 = cvt_pk_bf16(eB0, eB1), dB1 = cvt_pk_bf16(eB2, eB3);
    if ((f & 1) == 0){
      paA0 = dA0; paA1 = dA1; paB0 = dB0; paB1 = dB1;
    } else {
      i32x4 ta = {paA0, paA1, dA0, dA1};
      i32x4 tb = {paB0, paB1, dB0, dB1};
      bf16x8 a01A = __builtin_bit_cast(bf16x8, ta);
      bf16x8 a01B = __builtin_bit_cast(bf16x8, tb);
      #pragma unroll
      for (int dt = 0; dt < 4; ++dt){
        oaccA[dt] = __builtin_amdgcn_mfma_f32_16x16x32_bf16(a01A, vpre[dt], oaccA[dt], 0, 0, 0);
        oaccB[dt] = __builtin_amdgcn_mfma_f32_16x16x32_bf16(a01B, vpre[dt], oaccB[dt], 0, 0, 0);
      }
    }
    kf0 = nkf0; kf1 = nkf1;
  }

  rsumA += __shfl_xor(rsumA, 16);
  rsumA += __shfl_xor(rsumA, 32);
  rsumB += __shfl_xor(rsumB, 16);
  rsumB += __shfl_xor(rsumB, 32);
  float irA  = 1.0f / rsumA;
  float irB  = 1.0f / rsumB;

  if (quad == 0){
    irw[((n*NH + w) << 10) + q0 + l16]      = irA;
    irw[((n*NH + w) << 10) + q0 + 16 + l16] = irB;
  }

  float irqA[4], irqB[4];
  #pragma unroll
  for (int j = 0; j < 4; ++j){
    irqA[j] = __shfl(irA, quad*4 + j);
    irqB[j] = __shfl(irB, quad*4 + j);
  }
  #pragma unroll
  for (int dt = 0; dt < 4; ++dt){
    float* opA = out + ((size_t)(n*LQ + q0 + quad*4))*DM + w*DH + dt*16 + l16;
    opA[0]      = oaccA[dt][0] * irqA[0];
    opA[DM]     = oaccA[dt][1] * irqA[1];
    opA[2*DM]   = oaccA[dt][2] * irqA[2];
    opA[3*DM]   = oaccA[dt][3] * irqA[3];
    float* opB = opA + (size_t)16*DM;
    opB[0]      = oaccB[dt][0] * irqB[0];
    opB[DM]     = oaccB[dt][1] * irqB[1];
    opB[2*DM]   = oaccB[dt][2] * irqB[2];
    opB[3*DM]   = oaccB[dt][3] * irqB[3];
  }
}

// ---------------- k3: attn mean, head-outer, register accumulate ------------
// block b: n=b&7, qt=(b>>3)&63 (16-q tile), sh=b>>9 (s half).
// wave w8 owns s-strip [sh*512 + w8*64, +64); lane(l16,quad,j) -> q=l16,
// s = s0 + sub*16 + quad*4 + j. acc[sub] fp32 accumulates over 16 heads.
// No LDS, no barriers. launch_bounds(512,8) targets <=64 VGPR = 4 blk/CU.
__global__ __launch_bounds__(512, 8) void k3_attnmean(const short* __restrict__ bKw,
                                                      const float* __restrict__ irw,
                                                      float* __restrict__ attn){
  int tid  = threadIdx.x;
  int lane = tid & 63;
  int w8   = tid >> 6;
  int l16  = lane & 15;
  int quad = lane >> 4;
  int b  = blockIdx.x;
  int n  = b & 7;                       // XCD swizzle
  int qt = (b >> 3) & 63;
  int sh = b >> 9;
  int q0 = qt << 4;
  int s0 = sh*512 + w8*64;

  const float CE = 0.1803368801111244f;
  const f32x4 vzero = {0.f, 0.f, 0.f, 0.f};
  f32x4 acc[4] = {vzero, vzero, vzero, vzero};

  const short* nb = bKw + ((size_t)n*NH)*LQ*DH;
  for (int h = 0; h < NH; ++h){
    const short* hbp = nb + (size_t)h*LQ*DH;
    const short* qp  = hbp + (size_t)(q0 + l16)*DH + quad*8;
    bf16x8 qf0 = *(const bf16x8*)qp;
    bf16x8 qf1 = *(const bf16x8*)(qp + 32);
    float ir = irw[((n*NH + h) << 10) + q0 + l16];
    const short* kp = hbp + (size_t)(s0 + l16)*DH + quad*8;
    #pragma unroll
    for (int sub = 0; sub < 4; ++sub){
      bf16x8 k0 = *(const bf16x8*)kp;
      bf16x8 k1 = *(const bf16x8*)(kp + 32);
      kp += 16*DH;
      f32x4 st = vzero;
      st = __builtin_amdgcn_mfma_f32_16x16x32_bf16(k0, qf0, st, 0, 0, 0);
      st = __builtin_amdgcn_mfma_f32_16x16x32_bf16(k1, qf1, st, 0, 0, 0);
      acc[sub][0] += __builtin_amdgcn_exp2f(st[0]*CE) * ir;
      acc[sub][1] += __builtin_amdgcn_exp2f(st[1]*CE) * ir;
      acc[sub][2] += __builtin_amdgcn_exp2f(st[2]*CE) * ir;
      acc[sub][3] += __builtin_amdgcn_exp2f(st[3]*CE) * ir;
    }
  }
  #pragma unroll
  for (int sub = 0; sub < 4; ++sub){
    f32x4 o = acc[sub];
    o[0] *= 0.0625f; o[1] *= 0.0625f; o[2] *= 0.0625f; o[3] *= 0.0625f;
    *(f32x4*)(&attn[((size_t)((n << 10) + q0 + l16))*LQ + s0 + sub*16 + quad*4]) = o;
  }
}

// ---------------- fallback: monolithic k2 (R13, verified 180us) -------------
__global__ __launch_bounds__(1024, 4) void k2_attn(const short* __restrict__ bKw,
                                                   const short* __restrict__ bTw,
                                                   float* __restrict__ out,
                                                   float* __restrict__ attn){
  __shared__ short AS[2*NH*16*AW];
  int tid  = threadIdx.x;
  int lane = tid & 63;
  int w    = tid >> 6;
  int l16  = lane & 15;
  int quad = lane >> 4;
  int n  = blockIdx.x & 7;
  int q0 = (blockIdx.x >> 3) << 5;

  const float CE = 0.1803368801111244f;
  const f32x4 vzero = {0.f, 0.f, 0.f, 0.f};

  size_t hb = ((size_t)(n*NH + w))*LQ*DH;
  const short* kb  = bKw + hb + (size_t)l16*DH + quad*8;
  const short* kbp = bKw + hb + (size_t)((l16 >> 2)*8 + (l16 & 3))*DH + quad*8;

  bf16x8 qfA0 = *(const bf16x8*)(kb + (size_t)q0*DH);
  bf16x8 qfA1 = *(const bf16x8*)(kb + (size_t)q0*DH + 32);
  bf16x8 qfB0 = *(const bf16x8*)(kb + (size_t)(q0+16)*DH);
  bf16x8 qfB1 = *(const bf16x8*)(kb + (size_t)(q0+16)*DH + 32);

  f32x4 oaccA[4], oaccB[4];
  #pragma unroll
  for (int dt = 0; dt < 4; ++dt){ oaccA[dt] = vzero; oaccB[dt] = vzero; }
  float rsumA = 0.f, rsumB = 0.f;

  bf16x8 kf0 = *(const bf16x8*)kbp;
  bf16x8 kf1 = *(const bf16x8*)(kbp + 32);
  bf16x8 vpre[4];
  int paA0 = 0, paA1 = 0, paB0 = 0, paB1 = 0;
  for (int f = 0; f < 64; ++f){
    int fn = (f + 1) & 63;
    int tn = (fn >> 1)*32 + (fn & 1)*4;
    const short* nkp = kbp + (size_t)tn*DH;
    bf16x8 nkf0 = *(const bf16x8*)nkp;
    bf16x8 nkf1 = *(const bf16x8*)(nkp + 32);
    if ((f & 1) == 0){
      int vwin = f >> 1;
      #pragma unroll
      for (int dt = 0; dt < 4; ++dt){
        const short* vp = bTw + ((size_t)((n*32 + vwin)*DM + w*DH + dt*16 + l16))*32 + quad*8;
        vpre[dt] = *(const bf16x8*)vp;
      }
    }
    f32x4 stA = vzero, stB = vzero;
    stA = __builtin_amdgcn_mfma_f32_16x16x32_bf16(kf0, qfA0, stA, 0, 0, 0);
    stA = __builtin_amdgcn_mfma_f32_16x16x32_bf16(kf1, qfA1, stA, 0, 0, 0);
    stB = __builtin_amdgcn_mfma_f32_16x16x32_bf16(kf0, qfB0, stB, 0, 0, 0);
    stB = __builtin_amdgcn_mfma_f32_16x16x32_bf16(kf1, qfB1, stB, 0, 0, 0);
    float eA0 = __builtin_amdgcn_exp2f(stA[0]*CE);
    float eA1 = __builtin_amdgcn_exp2f(stA[1]*CE);
    float eA2 = __builtin_amdgcn_exp2f(stA[2]*CE);
    float eA3 = __builtin_amdgcn_exp2f(stA[3]*CE);
    float eB0 = __builtin_amdgcn_exp2f(stB[0]*CE);
    float eB1 = __builtin_amdgcn_exp2f(stB[1]*CE);
    float eB2 = __builtin_amdgcn_exp2f(stB[2]*CE);
    float eB3 = __builtin_amdgcn_exp2f(stB[3]*CE);
    rsumA += (eA0 + eA1) + (eA2 + eA3);
    rsumB += (eB0 + eB1) + (eB2 + eB3);
    int dA0 = cvt_pk_bf16(eA0, eA1), dA1 = cvt_pk_bf16(eA2, eA3);
    int dB0 = cvt_pk_bf16(eB0, eB1), dB1 = cvt_pk_bf16(eB2, eB3);
    if ((f & 1) == 0){
      paA0 = dA0; paA1 = dA1; paB0 = dB0; paB1 = dB1;
    } else {
      i32x4 ta = {paA0, paA1, dA0, dA1};
      i32x4 tb = {paB0, paB1, dB0, dB1};
      bf16x8 a01A = __builtin_bit_cast(bf16x8, ta);
      bf16x8 a01B = __builtin_bit_cast(bf16x8, tb);
      #pragma unroll
      for (int dt = 0; dt < 4; ++dt){
        oaccA[dt] = __builtin_amdgcn_mfma_f32_16x16x32_bf16(a01A, vpre[dt], oaccA[dt], 0, 0, 0);
        oaccB[dt] = __builtin_amdgcn_mfma_f32_16x16x32_bf16(a01B, vpre[dt], oaccB[dt], 0, 0, 0);
      }
    }
    kf0 = nkf0; kf1 = nkf1;
  }

  rsumA += __shfl_xor(rsumA, 16);
  rsumA += __shfl_xor(rsumA, 32);
  rsumB += __shfl_xor(rsumB, 16);
  rsumB += __shfl_xor(rsumB, 32);
  float irA  = 1.0f / rsumA;
  float irB  = 1.0f / rsumB;
  float irsA = irA * 0.0625f;
  float irsB = irB * 0.0625f;

  float irqA[4], irqB[4];
  #pragma unroll
  for (int j = 0; j < 4; ++j){
    irqA[j] = __shfl(irA, quad*4 + j);
    irqB[j] = __shfl(irB, quad*4 + j);
  }
  #pragma unroll
  for (int dt = 0; dt < 4; ++dt){
    float* opA = out + ((size_t)(n*LQ + q0 + quad*4))*DM + w*DH + dt*16 + l16;
    opA[0]      = oaccA[dt][0] * irqA[0];
    opA[DM]     = oaccA[dt][1] * irqA[1];
    opA[2*DM]   = oaccA[dt][2] * irqA[2];
    opA[3*DM]   = oaccA[dt][3] * irqA[3];
    float* opB = opA + (size_t)16*DM;
    opB[0]      = oaccB[dt][0] * irqB[0];
    opB[DM]     = oaccB[dt][1] * irqB[1];
    opB[2*DM]   = oaccB[dt][2] * irqB[2];
    opB[3*DM]   = oaccB[dt][3] * irqB[3];
  }

  short* AmineA = &AS[w*16*AW];
  short* AmineB = &AS[NH*16*AW + w*16*AW];
  for (int win = 0; win < 16; ++win){
    bf16x8 kw[4][2];
    #pragma unroll
    for (int sub = 0; sub < 4; ++sub){
      const short* kp = kb + (size_t)(win*64 + sub*16)*DH;
      kw[sub][0] = *(const bf16x8*)kp;
      kw[sub][1] = *(const bf16x8*)(kp + 32);
    }
    #pragma unroll
    for (int sub = 0; sub < 4; ++sub){
      f32x4 stA = vzero, stB = vzero;
      stA = __builtin_amdgcn_mfma_f32_16x16x32_bf16(kw[sub][0], qfA0, stA, 0, 0, 0);
      stA = __builtin_amdgcn_mfma_f32_16x16x32_bf16(kw[sub][1], qfA1, stA, 0, 0, 0);
      stB = __builtin_amdgcn_mfma_f32_16x16x32_bf16(kw[sub][0], qfB0, stB, 0, 0, 0);
      stB = __builtin_amdgcn_mfma_f32_16x16x32_bf16(kw[sub][1], qfB1, stB, 0, 0, 0);
      float gA0 = __builtin_amdgcn_exp2f(stA[0]*CE) * irsA;
      float gA1 = __builtin_amdgcn_exp2f(stA[1]*CE) * irsA;
      float gA2 = __builtin_amdgcn_exp2f(stA[2]*CE) * irsA;
      float gA3 = __builtin_amdgcn_exp2f(stA[3]*CE) * irsA;
      float gB0 = __builtin_amdgcn_exp2f(stB[0]*CE) * irsB;
      float gB1 = __builtin_amdgcn_exp2f(stB[1]*CE) * irsB;
      float gB2 = __builtin_amdgcn_exp2f(stB[2]*CE) * irsB;
      float gB3 = __builtin_amdgcn_exp2f(stB[3]*CE) * irsB;
      i32x2 wvA = {cvt_pk_bf16(gA0, gA1), cvt_pk_bf16(gA2, gA3)};
      i32x2 wvB = {cvt_pk_bf16(gB0, gB1), cvt_pk_bf16(gB2, gB3)};
      *(i32x2*)(&AmineA[l16*AW + sub*16 + quad*4]) = wvA;
      *(i32x2*)(&AmineB[l16*AW + sub*16 + quad*4]) = wvB;
    }
    __syncthreads();
    {
      int qr = tid >> 6;
      int s  = tid & 63;
      float sum0 = 0.f, sum1 = 0.f;
      #pragma unroll
      for (int ww = 0; ww < NH; ++ww){
        sum0 += bf2f(AS[ww*16*AW + qr*AW + s]);
        sum1 += bf2f(AS[NH*16*AW + ww*16*AW + qr*AW + s]);
      }
      attn[((size_t)(n*LQ + q0 + qr))*LQ + win*64 + s]      = sum0;
      attn[((size_t)(n*LQ + q0 + 16 + qr))*LQ + win*64 + s] = sum1;
    }
    __syncthreads();
  }
}

extern "C" void kernel_launch(void* const* d_in, const int* in_sizes, int n_in,
                              void* d_out, int out_size, void* d_ws, size_t ws_size,
                              hipStream_t stream){
  const float* in = (const float*)d_in[0];
  float* out  = (float*)d_out;
  float* attn = out + (size_t)NB*LQ*DM;
  short* bKw = (short*)d_ws;
  size_t half = (size_t)NB*LQ*DM;          // 8 Mi elements
  short* bTw = bKw + half;

  k0_convert<<<dim3(512), dim3(256), 0, stream>>>(in, bKw, bTw);

  size_t need = 2*half*sizeof(short) + (size_t)NB*NH*LQ*sizeof(float);
  if (ws_size >= need){
    float* irw = (float*)(bTw + half);
    k2a_fwd   <<<dim3(256),  dim3(1024), 0, stream>>>(bKw, bTw, out, irw);
    k3_attnmean<<<dim3(1024), dim3(512), 0, stream>>>(bKw, irw, attn);
  } else {
    k2_attn   <<<dim3(256),  dim3(1024), 0, stream>>>(bKw, bTw, out, attn);
  }
}

// Round 9
// 323.867 us; speedup vs baseline: 1.0006x; 1.0006x over previous
//
#include <hip/hip_runtime.h>

// AttentionLayer: N=8, L=1024, D_MODEL=1024, H=16, d_head=64.
// out  = softmax(QK^T/8)V reshaped   (8,1024,1024) fp32
// attn = mean over heads of softmax  (8,1024,1024) fp32, after out.
//
// R14 split diagnosis: k2a (loop1) ~100-110us, k3 (attn mean) 152.7us with
//      VGPR=24 -> compiler serialized every load->use (launch_bounds(512,8)
//      register cap). k3's true floor: ~8us MFMA + ~4us exp + ~12us L2.
// R15: k3 rewritten. (a) 2-deep head pipeline with static ping-pong buffers
//      kA/kB (loads of head h+1 issue under compute of head h);
//      (b) launch_bounds(512,4) -> 128 VGPR budget for the ~110-reg pipeline;
//      (c) block remap: waves = q-subtiles, block = one s-strip, so all 8
//      waves share the same K lines (L1/L2 dedupe, ~384KB/block vs 1MB).
//      k0 / k2a / fallback unchanged (isolate the k3 change).

#define NB 8
#define LQ 1024
#define DM 1024
#define NH 16
#define DH 64
#define AW 68           // attn stage row stride (shorts), fallback kernel
#define TR 528          // k0 LDS row stride (shorts)

typedef __attribute__((ext_vector_type(4))) float f32x4;
typedef __attribute__((ext_vector_type(8))) short bf16x8;
typedef __attribute__((ext_vector_type(4))) short bf16x4;
typedef __attribute__((ext_vector_type(4))) int   i32x4;
typedef __attribute__((ext_vector_type(2))) int   i32x2;

__device__ inline short f2bf(float f){
  unsigned u = __builtin_bit_cast(unsigned, f);
  u += 0x7fffu + ((u >> 16) & 1u);   // RNE (inputs finite)
  return (short)(u >> 16);
}
__device__ inline float bf2f(short s){
  unsigned u = ((unsigned)(unsigned short)s) << 16;
  return __builtin_bit_cast(float, u);
}
__device__ inline int cvt_pk_bf16(float lo, float hi){
  int r;
  asm("v_cvt_pk_bf16_f32 %0, %1, %2" : "=v"(r) : "v"(lo), "v"(hi));
  return r;
}

// ---------------- k0: fp32 -> bf16, coalesced writes (R13) ------------------
__global__ __launch_bounds__(256) void k0_convert(const float* __restrict__ in,
                                                  short* __restrict__ bKw,
                                                  short* __restrict__ bTw){
  __shared__ short T[32*TR];
  int b   = blockIdx.x;
  int dh  = b & 1;
  int win = (b >> 1) & 31;
  int n   = b >> 6;
  int tid = threadIdx.x;
  int w    = tid >> 6;
  int lane = tid & 63;

  {
    int s  = tid >> 3;
    int c0 = (tid & 7) << 2;
    const float* src = in + ((size_t)(n*LQ + win*32 + s))*DM + dh*512;
    #pragma unroll
    for (int p = 0; p < 16; ++p){
      int c = p*32 + c0;
      f32x4 f = *(const f32x4*)(src + c);
      bf16x4 v = {f2bf(f.x), f2bf(f.y), f2bf(f.z), f2bf(f.w)};
      *(bf16x4*)&T[s*TR + c] = v;
    }
  }
  __syncthreads();

  {
    int r8 = lane >> 3;
    int cc = (lane & 7) << 3;
    #pragma unroll
    for (int pass = 0; pass < 8; ++pass){
      int t  = pass*4 + w;
      int hl = t >> 2;
      int rg = t & 3;
      int s  = rg*8 + r8;
      bf16x8 v = *(const bf16x8*)&T[s*TR + hl*64 + cc];
      int h = dh*8 + hl;
      size_t dst = ((size_t)((n*NH + h)*LQ + win*32 + s))*DH + cc;
      *(bf16x8*)(bKw + dst) = v;
    }
  }

  {
    #pragma unroll
    for (int pass = 0; pass < 8; ++pass){
      int t    = pass*4 + w;
      int dloc = t*16 + (lane >> 2);
      int sl8  = (lane & 3) << 3;
      short t0 = T[(sl8+0)*TR + dloc];
      short t1 = T[(sl8+1)*TR + dloc];
      short t2 = T[(sl8+2)*TR + dloc];
      short t3 = T[(sl8+3)*TR + dloc];
      short t4 = T[(sl8+4)*TR + dloc];
      short t5 = T[(sl8+5)*TR + dloc];
      short t6 = T[(sl8+6)*TR + dloc];
      short t7 = T[(sl8+7)*TR + dloc];
      bf16x8 v = {t0, t1, t2, t3, t4, t5, t6, t7};
      int d = dh*512 + dloc;
      size_t dst = ((size_t)((n*32 + win)*DM + d))*32 + sl8;
      *(bf16x8*)(bTw + dst) = v;
    }
  }
}

// ---------------- k2a: loop1 only (R10 datapath) + ir store -----------------
__global__ __launch_bounds__(1024, 4) void k2a_fwd(const short* __restrict__ bKw,
                                                   const short* __restrict__ bTw,
                                                   float* __restrict__ out,
                                                   float* __restrict__ irw){
  int tid  = threadIdx.x;
  int lane = tid & 63;
  int w    = tid >> 6;                  // wave id == head id
  int l16  = lane & 15;
  int quad = lane >> 4;
  int n  = blockIdx.x & 7;              // XCD swizzle
  int q0 = (blockIdx.x >> 3) << 5;      // 32 q-rows per block

  const float CE = 0.1803368801111244f; // 0.125 * log2(e)
  const f32x4 vzero = {0.f, 0.f, 0.f, 0.f};

  size_t hb = ((size_t)(n*NH + w))*LQ*DH;
  const short* kb  = bKw + hb + (size_t)l16*DH + quad*8;
  const short* kbp = bKw + hb + (size_t)((l16 >> 2)*8 + (l16 & 3))*DH + quad*8;

  bf16x8 qfA0 = *(const bf16x8*)(kb + (size_t)q0*DH);
  bf16x8 qfA1 = *(const bf16x8*)(kb + (size_t)q0*DH + 32);
  bf16x8 qfB0 = *(const bf16x8*)(kb + (size_t)(q0+16)*DH);
  bf16x8 qfB1 = *(const bf16x8*)(kb + (size_t)(q0+16)*DH + 32);

  f32x4 oaccA[4], oaccB[4];
  #pragma unroll
  for (int dt = 0; dt < 4; ++dt){ oaccA[dt] = vzero; oaccB[dt] = vzero; }
  float rsumA = 0.f, rsumB = 0.f;

  bf16x8 kf0 = *(const bf16x8*)kbp;
  bf16x8 kf1 = *(const bf16x8*)(kbp + 32);
  bf16x8 vpre[4];
  int paA0 = 0, paA1 = 0, paB0 = 0, paB1 = 0;
  for (int f = 0; f < 64; ++f){
    int fn = (f + 1) & 63;
    int tn = (fn >> 1)*32 + (fn & 1)*4;
    const short* nkp = kbp + (size_t)tn*DH;
    bf16x8 nkf0 = *(const bf16x8*)nkp;
    bf16x8 nkf1 = *(const bf16x8*)(nkp + 32);
    if ((f & 1) == 0){
      int vwin = f >> 1;
      #pragma unroll
      for (int dt = 0; dt < 4; ++dt){
        const short* vp = bTw + ((size_t)((n*32 + vwin)*DM + w*DH + dt*16 + l16))*32 + quad*8;
        vpre[dt] = *(const bf16x8*)vp;
      }
    }
    f32x4 stA = vzero, stB = vzero;
    stA = __builtin_amdgcn_mfma_f32_16x16x32_bf16(kf0, qfA0, stA, 0, 0, 0);
    stA = __builtin_amdgcn_mfma_f32_16x16x32_bf16(kf1, qfA1, stA, 0, 0, 0);
    stB = __builtin_amdgcn_mfma_f32_16x16x32_bf16(kf0, qfB0, stB, 0, 0, 0);
    stB = __builtin_amdgcn_mfma_f32_16x16x32_bf16(kf1, qfB1, stB, 0, 0, 0);
    float eA0 = __builtin_amdgcn_exp2f(stA[0]*CE);
    float eA1 = __builtin_amdgcn_exp2f(stA[1]*CE);
    float eA2 = __builtin_amdgcn_exp2f(stA[2]*CE);
    float eA3 = __builtin_amdgcn_exp2f(stA[3]*CE);
    float eB0 = __builtin_amdgcn_exp2f(stB[0]*CE);
    float eB1 = __builtin_amdgcn_exp2f(stB[1]*CE);
    float eB2 = __builtin_amdgcn_exp2f(stB[2]*CE);
    float eB3 = __builtin_amdgcn_exp2f(stB[3]*CE);
    rsumA += (eA0 + eA1) + (eA2 + eA3);
    rsumB += (eB0 + eB1) + (eB2 + eB3);
    int dA0 = cvt_pk_bf16(eA0, eA1), dA1 = cvt_pk_bf16(eA2, eA3);
    int dB0 = cvt_pk_bf16(eB0, eB1), dB1 = cvt_pk_bf16(eB2, eB3);
    if ((f & 1) == 0){
      paA0 = dA0; paA1 = dA1; paB0 = dB0; paB1 = dB1;
    } else {
      i32x4 ta = {paA0, paA1, dA0, dA1};
      i32x4 tb = {paB0, paB1, dB0, dB1};
      bf16x8 a01A = __builtin_bit_cast(bf16x8, ta);
      bf16x8 a01B = __builtin_bit_cast(bf16x8, tb);
      #pragma unroll
      for (int dt = 0; dt < 4; ++dt){
        oaccA[dt] = __builtin_amdgcn_mfma_f32_16x16x32_bf16(a01A, vpre[dt], oaccA[dt], 0, 0, 0);
        oaccB[dt] = __builtin_amdgcn_mfma_f32_16x16x32_bf16(a01B, vpre[dt], oaccB[dt], 0, 0, 0);
      }
    }
    kf0 = nkf0; kf1 = nkf1;
  }

  rsumA += __shfl_xor(rsumA, 16);
  rsumA += __shfl_xor(rsumA, 32);
  rsumB += __shfl_xor(rsumB, 16);
  rsumB += __shfl_xor(rsumB, 32);
  float irA  = 1.0f / rsumA;
  float irB  = 1.0f / rsumB;

  if (quad == 0){
    irw[((n*NH + w) << 10) + q0 + l16]      = irA;
    irw[((n*NH + w) << 10) + q0 + 16 + l16] = irB;
  }

  float irqA[4], irqB[4];
  #pragma unroll
  for (int j = 0; j < 4; ++j){
    irqA[j] = __shfl(irA, quad*4 + j);
    irqB[j] = __shfl(irB, quad*4 + j);
  }
  #pragma unroll
  for (int dt = 0; dt < 4; ++dt){
    float* opA = out + ((size_t)(n*LQ + q0 + quad*4))*DM + w*DH + dt*16 + l16;
    opA[0]      = oaccA[dt][0] * irqA[0];
    opA[DM]     = oaccA[dt][1] * irqA[1];
    opA[2*DM]   = oaccA[dt][2] * irqA[2];
    opA[3*DM]   = oaccA[dt][3] * irqA[3];
    float* opB = opA + (size_t)16*DM;
    opB[0]      = oaccB[dt][0] * irqB[0];
    opB[DM]     = oaccB[dt][1] * irqB[1];
    opB[2*DM]   = oaccB[dt][2] * irqB[2];
    opB[3*DM]   = oaccB[dt][3] * irqB[3];
  }
}

// ---------------- k3: attn mean, head-outer, 2-deep pipelined ---------------
// block b: n=b&7, st=(b>>3)&15 (64-s strip), qg=b>>7 (128-q group).
// wave w8 owns q-rows [qg*128 + w8*16, +16): all 8 waves READ THE SAME K
// s-strip (L1/L2 dedupe). Head loop 2-deep ping-pong: kB/qB/irB loads for
// head h+1 issue before compute of head h. launch_bounds(512,4): 128-VGPR
// budget holds the ~110-reg pipeline without spills.
__global__ __launch_bounds__(512, 4) void k3_attnmean(const short* __restrict__ bKw,
                                                      const float* __restrict__ irw,
                                                      float* __restrict__ attn){
  int tid  = threadIdx.x;
  int lane = tid & 63;
  int w8   = tid >> 6;
  int l16  = lane & 15;
  int quad = lane >> 4;
  int b    = blockIdx.x;
  int n    = b & 7;                     // XCD swizzle
  int rest = b >> 3;
  int st   = rest & 15;                 // s-strip of 64
  int qg   = rest >> 4;                 // q-group of 128
  int q0 = qg*128 + w8*16;
  int s0 = st*64;

  const float CE = 0.1803368801111244f;
  const f32x4 vzero = {0.f, 0.f, 0.f, 0.f};
  f32x4 acc[4] = {vzero, vzero, vzero, vzero};

  const short* nb = bKw + ((size_t)n*NH)*LQ*DH;

  bf16x8 kA[8], kB[8], qA0, qA1, qB0, qB1;
  float irA_, irB_;

  auto ldhead = [&](bf16x8 (&K)[8], bf16x8& Q0, bf16x8& Q1, float& IR, int h){
    const short* hbp = nb + (size_t)h*LQ*DH;
    const short* qp  = hbp + (size_t)(q0 + l16)*DH + quad*8;
    Q0 = *(const bf16x8*)qp;
    Q1 = *(const bf16x8*)(qp + 32);
    IR = irw[((n*NH + h) << 10) + q0 + l16];
    const short* kp = hbp + (size_t)(s0 + l16)*DH + quad*8;
    #pragma unroll
    for (int sub = 0; sub < 4; ++sub){
      K[2*sub]   = *(const bf16x8*)kp;
      K[2*sub+1] = *(const bf16x8*)(kp + 32);
      kp += 16*DH;
    }
  };

  auto compute = [&](bf16x8 (&K)[8], bf16x8 Q0, bf16x8 Q1, float IR){
    #pragma unroll
    for (int sub = 0; sub < 4; ++sub){
      f32x4 stv = vzero;
      stv = __builtin_amdgcn_mfma_f32_16x16x32_bf16(K[2*sub],   Q0, stv, 0, 0, 0);
      stv = __builtin_amdgcn_mfma_f32_16x16x32_bf16(K[2*sub+1], Q1, stv, 0, 0, 0);
      acc[sub][0] += __builtin_amdgcn_exp2f(stv[0]*CE) * IR;
      acc[sub][1] += __builtin_amdgcn_exp2f(stv[1]*CE) * IR;
      acc[sub][2] += __builtin_amdgcn_exp2f(stv[2]*CE) * IR;
      acc[sub][3] += __builtin_amdgcn_exp2f(stv[3]*CE) * IR;
    }
  };

  ldhead(kA, qA0, qA1, irA_, 0);
  for (int hp = 0; hp < 8; ++hp){
    ldhead(kB, qB0, qB1, irB_, 2*hp + 1);
    compute(kA, qA0, qA1, irA_);
    if (hp < 7) ldhead(kA, qA0, qA1, irA_, 2*hp + 2);
    compute(kB, qB0, qB1, irB_);
  }

  #pragma unroll
  for (int sub = 0; sub < 4; ++sub){
    f32x4 o = acc[sub];
    o[0] *= 0.0625f; o[1] *= 0.0625f; o[2] *= 0.0625f; o[3] *= 0.0625f;
    *(f32x4*)(&attn[((size_t)((n << 10) + q0 + l16))*LQ + s0 + sub*16 + quad*4]) = o;
  }
}

// ---------------- fallback: monolithic k2 (R13, verified 180us) -------------
__global__ __launch_bounds__(1024, 4) void k2_attn(const short* __restrict__ bKw,
                                                   const short* __restrict__ bTw,
                                                   float* __restrict__ out,
                                                   float* __restrict__ attn){
  __shared__ short AS[2*NH*16*AW];
  int tid  = threadIdx.x;
  int lane = tid & 63;
  int w    = tid >> 6;
  int l16  = lane & 15;
  int quad = lane >> 4;
  int n  = blockIdx.x & 7;
  int q0 = (blockIdx.x >> 3) << 5;

  const float CE = 0.1803368801111244f;
  const f32x4 vzero = {0.f, 0.f, 0.f, 0.f};

  size_t hb = ((size_t)(n*NH + w))*LQ*DH;
  const short* kb  = bKw + hb + (size_t)l16*DH + quad*8;
  const short* kbp = bKw + hb + (size_t)((l16 >> 2)*8 + (l16 & 3))*DH + quad*8;

  bf16x8 qfA0 = *(const bf16x8*)(kb + (size_t)q0*DH);
  bf16x8 qfA1 = *(const bf16x8*)(kb + (size_t)q0*DH + 32);
  bf16x8 qfB0 = *(const bf16x8*)(kb + (size_t)(q0+16)*DH);
  bf16x8 qfB1 = *(const bf16x8*)(kb + (size_t)(q0+16)*DH + 32);

  f32x4 oaccA[4], oaccB[4];
  #pragma unroll
  for (int dt = 0; dt < 4; ++dt){ oaccA[dt] = vzero; oaccB[dt] = vzero; }
  float rsumA = 0.f, rsumB = 0.f;

  bf16x8 kf0 = *(const bf16x8*)kbp;
  bf16x8 kf1 = *(const bf16x8*)(kbp + 32);
  bf16x8 vpre[4];
  int paA0 = 0, paA1 = 0, paB0 = 0, paB1 = 0;
  for (int f = 0; f < 64; ++f){
    int fn = (f + 1) & 63;
    int tn = (fn >> 1)*32 + (fn & 1)*4;
    const short* nkp = kbp + (size_t)tn*DH;
    bf16x8 nkf0 = *(const bf16x8*)nkp;
    bf16x8 nkf1 = *(const bf16x8*)(nkp + 32);
    if ((f & 1) == 0){
      int vwin = f >> 1;
      #pragma unroll
      for (int dt = 0; dt < 4; ++dt){
        const short* vp = bTw + ((size_t)((n*32 + vwin)*DM + w*DH + dt*16 + l16))*32 + quad*8;
        vpre[dt] = *(const bf16x8*)vp;
      }
    }
    f32x4 stA = vzero, stB = vzero;
    stA = __builtin_amdgcn_mfma_f32_16x16x32_bf16(kf0, qfA0, stA, 0, 0, 0);
    stA = __builtin_amdgcn_mfma_f32_16x16x32_bf16(kf1, qfA1, stA, 0, 0, 0);
    stB = __builtin_amdgcn_mfma_f32_16x16x32_bf16(kf0, qfB0, stB, 0, 0, 0);
    stB = __builtin_amdgcn_mfma_f32_16x16x32_bf16(kf1, qfB1, stB, 0, 0, 0);
    float eA0 = __builtin_amdgcn_exp2f(stA[0]*CE);
    float eA1 = __builtin_amdgcn_exp2f(stA[1]*CE);
    float eA2 = __builtin_amdgcn_exp2f(stA[2]*CE);
    float eA3 = __builtin_amdgcn_exp2f(stA[3]*CE);
    float eB0 = __builtin_amdgcn_exp2f(stB[0]*CE);
    float eB1 = __builtin_amdgcn_exp2f(stB[1]*CE);
    float eB2 = __builtin_amdgcn_exp2f(stB[2]*CE);
    float eB3 = __builtin_amdgcn_exp2f(stB[3]*CE);
    rsumA += (eA0 + eA1) + (eA2 + eA3);
    rsumB += (eB0 + eB1) + (eB2 + eB3);
    int dA0 = cvt_pk_bf16(eA0, eA1), dA1 = cvt_pk_bf16(eA2, eA3);
    int dB0 = cvt_pk_bf16(eB0, eB1), dB1 = cvt_pk_bf16(eB2, eB3);
    if ((f & 1) == 0){
      paA0 = dA0; paA1 = dA1; paB0 = dB0; paB1 = dB1;
    } else {
      i32x4 ta = {paA0, paA1, dA0, dA1};
      i32x4 tb = {paB0, paB1, dB0, dB1};
      bf16x8 a01A = __builtin_bit_cast(bf16x8, ta);
      bf16x8 a01B = __builtin_bit_cast(bf16x8, tb);
      #pragma unroll
      for (int dt = 0; dt < 4; ++dt){
        oaccA[dt] = __builtin_amdgcn_mfma_f32_16x16x32_bf16(a01A, vpre[dt], oaccA[dt], 0, 0, 0);
        oaccB[dt] = __builtin_amdgcn_mfma_f32_16x16x32_bf16(a01B, vpre[dt], oaccB[dt], 0, 0, 0);
      }
    }
    kf0 = nkf0; kf1 = nkf1;
  }

  rsumA += __shfl_xor(rsumA, 16);
  rsumA += __shfl_xor(rsumA, 32);
  rsumB += __shfl_xor(rsumB, 16);
  rsumB += __shfl_xor(rsumB, 32);
  float irA  = 1.0f / rsumA;
  float irB  = 1.0f / rsumB;
  float irsA = irA * 0.0625f;
  float irsB = irB * 0.0625f;

  float irqA[4], irqB[4];
  #pragma unroll
  for (int j = 0; j < 4; ++j){
    irqA[j] = __shfl(irA, quad*4 + j);
    irqB[j] = __shfl(irB, quad*4 + j);
  }
  #pragma unroll
  for (int dt = 0; dt < 4; ++dt){
    float* opA = out + ((size_t)(n*LQ + q0 + quad*4))*DM + w*DH + dt*16 + l16;
    opA[0]      = oaccA[dt][0] * irqA[0];
    opA[DM]     = oaccA[dt][1] * irqA[1];
    opA[2*DM]   = oaccA[dt][2] * irqA[2];
    opA[3*DM]   = oaccA[dt][3] * irqA[3];
    float* opB = opA + (size_t)16*DM;
    opB[0]      = oaccB[dt][0] * irqB[0];
    opB[DM]     = oaccB[dt][1] * irqB[1];
    opB[2*DM]   = oaccB[dt][2] * irqB[2];
    opB[3*DM]   = oaccB[dt][3] * irqB[3];
  }

  short* AmineA = &AS[w*16*AW];
  short* AmineB = &AS[NH*16*AW + w*16*AW];
  for (int win = 0; win < 16; ++win){
    bf16x8 kw[4][2];
    #pragma unroll
    for (int sub = 0; sub < 4; ++sub){
      const short* kp = kb + (size_t)(win*64 + sub*16)*DH;
      kw[sub][0] = *(const bf16x8*)kp;
      kw[sub][1] = *(const bf16x8*)(kp + 32);
    }
    #pragma unroll
    for (int sub = 0; sub < 4; ++sub){
      f32x4 stA = vzero, stB = vzero;
      stA = __builtin_amdgcn_mfma_f32_16x16x32_bf16(kw[sub][0], qfA0, stA, 0, 0, 0);
      stA = __builtin_amdgcn_mfma_f32_16x16x32_bf16(kw[sub][1], qfA1, stA, 0, 0, 0);
      stB = __builtin_amdgcn_mfma_f32_16x16x32_bf16(kw[sub][0], qfB0, stB, 0, 0, 0);
      stB = __builtin_amdgcn_mfma_f32_16x16x32_bf16(kw[sub][1], qfB1, stB, 0, 0, 0);
      float gA0 = __builtin_amdgcn_exp2f(stA[0]*CE) * irsA;
      float gA1 = __builtin_amdgcn_exp2f(stA[1]*CE) * irsA;
      float gA2 = __builtin_amdgcn_exp2f(stA[2]*CE) * irsA;
      float gA3 = __builtin_amdgcn_exp2f(stA[3]*CE) * irsA;
      float gB0 = __builtin_amdgcn_exp2f(stB[0]*CE) * irsB;
      float gB1 = __builtin_amdgcn_exp2f(stB[1]*CE) * irsB;
      float gB2 = __builtin_amdgcn_exp2f(stB[2]*CE) * irsB;
      float gB3 = __builtin_amdgcn_exp2f(stB[3]*CE) * irsB;
      i32x2 wvA = {cvt_pk_bf16(gA0, gA1), cvt_pk_bf16(gA2, gA3)};
      i32x2 wvB = {cvt_pk_bf16(gB0, gB1), cvt_pk_bf16(gB2, gB3)};
      *(i32x2*)(&AmineA[l16*AW + sub*16 + quad*4]) = wvA;
      *(i32x2*)(&AmineB[l16*AW + sub*16 + quad*4]) = wvB;
    }
    __syncthreads();
    {
      int qr = tid >> 6;
      int s  = tid & 63;
      float sum0 = 0.f, sum1 = 0.f;
      #pragma unroll
      for (int ww = 0; ww < NH; ++ww){
        sum0 += bf2f(AS[ww*16*AW + qr*AW + s]);
        sum1 += bf2f(AS[NH*16*AW + ww*16*AW + qr*AW + s]);
      }
      attn[((size_t)(n*LQ + q0 + qr))*LQ + win*64 + s]      = sum0;
      attn[((size_t)(n*LQ + q0 + 16 + qr))*LQ + win*64 + s] = sum1;
    }
    __syncthreads();
  }
}

extern "C" void kernel_launch(void* const* d_in, const int* in_sizes, int n_in,
                              void* d_out, int out_size, void* d_ws, size_t ws_size,
                              hipStream_t stream){
  const float* in = (const float*)d_in[0];
  float* out  = (float*)d_out;
  float* attn = out + (size_t)NB*LQ*DM;
  short* bKw = (short*)d_ws;
  size_t half = (size_t)NB*LQ*DM;          // 8 Mi elements
  short* bTw = bKw + half;

  k0_convert<<<dim3(512), dim3(256), 0, stream>>>(in, bKw, bTw);

  size_t need = 2*half*sizeof(short) + (size_t)NB*NH*LQ*sizeof(float);
  if (ws_size >= need){
    float* irw = (float*)(bTw + half);
    k2a_fwd   <<<dim3(256),  dim3(1024), 0, stream>>>(bKw, bTw, out, irw);
    k3_attnmean<<<dim3(1024), dim3(512), 0, stream>>>(bKw, irw, attn);
  } else {
    k2_attn   <<<dim3(256),  dim3(1024), 0, stream>>>(bKw, bTw, out, attn);
  }
}

// Round 10
// 260.646 us; speedup vs baseline: 1.2433x; 1.2426x over previous
//
#include <hip/hip_runtime.h>

// AttentionLayer: N=8, L=1024, D_MODEL=1024, H=16, d_head=64.
// out  = softmax(QK^T/8)V reshaped   (8,1024,1024) fp32
// attn = mean over heads of softmax  (8,1024,1024) fp32, after out.
//
// R14/R15 split diagnosis: loop1 ~100us, loop2 ~80us; standalone attn-mean
//      restructure (k3) = 151us >> monolith loop2 -> splitting is a loss;
//      TLP (73% vs 36% occ, same time) and compiler-side pipelining both
//      null. Best = R13 monolith 251.1us total, k2 = 180.3us.
// R16: back to R13 monolith; attack loop2's BARRIER-SYNC SPREAD.
//      loop2 was 16 wins x 2 __syncthreads across 16 waves = 32 barriers;
//      12000 cy/window for ~2000 cy of work -> sync-spread dominated.
//      New loop2: stage 2 windows (128 s) for both q-tiles of all 16 heads
//      into AS2[512][136] (136 KB LDS), then 1 barrier + one vectorized
//      reduce (b64 LDS reads, f32x4 coalesced stores) + 1 barrier.
//      8 chunks x 2 barriers = 16 barriers (was 32), 2 windows of
//      independent staging between syncs. Loop1/epilogue/k0 unchanged.
// ws: 32 MB (bKw + bTw).

#define NB 8
#define LQ 1024
#define DM 1024
#define NH 16
#define DH 64
#define TR 528          // k0 LDS row stride (shorts)
#define RW 136          // loop2 stage row stride (shorts): 128 s + 8 pad

typedef __attribute__((ext_vector_type(4))) float f32x4;
typedef __attribute__((ext_vector_type(8))) short bf16x8;
typedef __attribute__((ext_vector_type(4))) short bf16x4;
typedef __attribute__((ext_vector_type(4))) int   i32x4;
typedef __attribute__((ext_vector_type(2))) int   i32x2;

__device__ inline short f2bf(float f){
  unsigned u = __builtin_bit_cast(unsigned, f);
  u += 0x7fffu + ((u >> 16) & 1u);   // RNE (inputs finite)
  return (short)(u >> 16);
}
__device__ inline float bf2f(short s){
  unsigned u = ((unsigned)(unsigned short)s) << 16;
  return __builtin_bit_cast(float, u);
}
__device__ inline int cvt_pk_bf16(float lo, float hi){
  int r;
  asm("v_cvt_pk_bf16_f32 %0, %1, %2" : "=v"(r) : "v"(lo), "v"(hi));
  return r;
}

// ---------------- k0: fp32 -> bf16, coalesced writes (R13) ------------------
__global__ __launch_bounds__(256) void k0_convert(const float* __restrict__ in,
                                                  short* __restrict__ bKw,
                                                  short* __restrict__ bTw){
  __shared__ short T[32*TR];
  int b   = blockIdx.x;
  int dh  = b & 1;
  int win = (b >> 1) & 31;
  int n   = b >> 6;
  int tid = threadIdx.x;
  int w    = tid >> 6;
  int lane = tid & 63;

  {
    int s  = tid >> 3;
    int c0 = (tid & 7) << 2;
    const float* src = in + ((size_t)(n*LQ + win*32 + s))*DM + dh*512;
    #pragma unroll
    for (int p = 0; p < 16; ++p){
      int c = p*32 + c0;
      f32x4 f = *(const f32x4*)(src + c);
      bf16x4 v = {f2bf(f.x), f2bf(f.y), f2bf(f.z), f2bf(f.w)};
      *(bf16x4*)&T[s*TR + c] = v;
    }
  }
  __syncthreads();

  {
    int r8 = lane >> 3;
    int cc = (lane & 7) << 3;
    #pragma unroll
    for (int pass = 0; pass < 8; ++pass){
      int t  = pass*4 + w;
      int hl = t >> 2;
      int rg = t & 3;
      int s  = rg*8 + r8;
      bf16x8 v = *(const bf16x8*)&T[s*TR + hl*64 + cc];
      int h = dh*8 + hl;
      size_t dst = ((size_t)((n*NH + h)*LQ + win*32 + s))*DH + cc;
      *(bf16x8*)(bKw + dst) = v;
    }
  }

  {
    #pragma unroll
    for (int pass = 0; pass < 8; ++pass){
      int t    = pass*4 + w;
      int dloc = t*16 + (lane >> 2);
      int sl8  = (lane & 3) << 3;
      short t0 = T[(sl8+0)*TR + dloc];
      short t1 = T[(sl8+1)*TR + dloc];
      short t2 = T[(sl8+2)*TR + dloc];
      short t3 = T[(sl8+3)*TR + dloc];
      short t4 = T[(sl8+4)*TR + dloc];
      short t5 = T[(sl8+5)*TR + dloc];
      short t6 = T[(sl8+6)*TR + dloc];
      short t7 = T[(sl8+7)*TR + dloc];
      bf16x8 v = {t0, t1, t2, t3, t4, t5, t6, t7};
      int d = dh*512 + dloc;
      size_t dst = ((size_t)((n*32 + win)*DM + d))*32 + sl8;
      *(bf16x8*)(bTw + dst) = v;
    }
  }
}

// ---------------- k2: one wave per head, two q-tiles per wave ---------------
// loop1: R10 datapath (permuted K fragments, zero LDS, no barriers).
// loop2 v2: 8 chunks of 128 s; stage both q-tiles of all heads into
// AS2[(h*32+ql)*RW + scol] (bf16), 1 barrier, vectorized 16-head reduce,
// 1 barrier. 16 barriers total vs 32 in R13.
__global__ __launch_bounds__(1024, 4) void k2_attn(const short* __restrict__ bKw,
                                                   const short* __restrict__ bTw,
                                                   float* __restrict__ out,
                                                   float* __restrict__ attn){
  __shared__ short AS2[512*RW];         // 139264 B (loop2 only)
  int tid  = threadIdx.x;
  int lane = tid & 63;
  int w    = tid >> 6;                  // wave id == head id
  int l16  = lane & 15;
  int quad = lane >> 4;
  int n  = blockIdx.x & 7;              // XCD swizzle
  int q0 = (blockIdx.x >> 3) << 5;      // 32 q-rows per block

  const float CE = 0.1803368801111244f; // 0.125 * log2(e)
  const f32x4 vzero = {0.f, 0.f, 0.f, 0.f};

  size_t hb = ((size_t)(n*NH + w))*LQ*DH;
  const short* kb  = bKw + hb + (size_t)l16*DH + quad*8;
  const short* kbp = bKw + hb + (size_t)((l16 >> 2)*8 + (l16 & 3))*DH + quad*8;

  bf16x8 qfA0 = *(const bf16x8*)(kb + (size_t)q0*DH);
  bf16x8 qfA1 = *(const bf16x8*)(kb + (size_t)q0*DH + 32);
  bf16x8 qfB0 = *(const bf16x8*)(kb + (size_t)(q0+16)*DH);
  bf16x8 qfB1 = *(const bf16x8*)(kb + (size_t)(q0+16)*DH + 32);

  f32x4 oaccA[4], oaccB[4];
  #pragma unroll
  for (int dt = 0; dt < 4; ++dt){ oaccA[dt] = vzero; oaccB[dt] = vzero; }
  float rsumA = 0.f, rsumB = 0.f;

  // ---- loop1: QK + exp (unnormalized) + PV, no barriers, no LDS ----
  bf16x8 kf0 = *(const bf16x8*)kbp;
  bf16x8 kf1 = *(const bf16x8*)(kbp + 32);
  bf16x8 vpre[4];
  int paA0 = 0, paA1 = 0, paB0 = 0, paB1 = 0;
  for (int f = 0; f < 64; ++f){
    int fn = (f + 1) & 63;
    int tn = (fn >> 1)*32 + (fn & 1)*4;
    const short* nkp = kbp + (size_t)tn*DH;
    bf16x8 nkf0 = *(const bf16x8*)nkp;
    bf16x8 nkf1 = *(const bf16x8*)(nkp + 32);
    if ((f & 1) == 0){
      int vwin = f >> 1;
      #pragma unroll
      for (int dt = 0; dt < 4; ++dt){
        const short* vp = bTw + ((size_t)((n*32 + vwin)*DM + w*DH + dt*16 + l16))*32 + quad*8;
        vpre[dt] = *(const bf16x8*)vp;
      }
    }
    f32x4 stA = vzero, stB = vzero;
    stA = __builtin_amdgcn_mfma_f32_16x16x32_bf16(kf0, qfA0, stA, 0, 0, 0);
    stA = __builtin_amdgcn_mfma_f32_16x16x32_bf16(kf1, qfA1, stA, 0, 0, 0);
    stB = __builtin_amdgcn_mfma_f32_16x16x32_bf16(kf0, qfB0, stB, 0, 0, 0);
    stB = __builtin_amdgcn_mfma_f32_16x16x32_bf16(kf1, qfB1, stB, 0, 0, 0);
    float eA0 = __builtin_amdgcn_exp2f(stA[0]*CE);
    float eA1 = __builtin_amdgcn_exp2f(stA[1]*CE);
    float eA2 = __builtin_amdgcn_exp2f(stA[2]*CE);
    float eA3 = __builtin_amdgcn_exp2f(stA[3]*CE);
    float eB0 = __builtin_amdgcn_exp2f(stB[0]*CE);
    float eB1 = __builtin_amdgcn_exp2f(stB[1]*CE);
    float eB2 = __builtin_amdgcn_exp2f(stB[2]*CE);
    float eB3 = __builtin_amdgcn_exp2f(stB[3]*CE);
    rsumA += (eA0 + eA1) + (eA2 + eA3);
    rsumB += (eB0 + eB1) + (eB2 + eB3);
    int dA0 = cvt_pk_bf16(eA0, eA1), dA1 = cvt_pk_bf16(eA2, eA3);
    int dB0 = cvt_pk_bf16(eB0, eB1), dB1 = cvt_pk_bf16(eB2, eB3);
    if ((f & 1) == 0){
      paA0 = dA0; paA1 = dA1; paB0 = dB0; paB1 = dB1;
    } else {
      i32x4 ta = {paA0, paA1, dA0, dA1};
      i32x4 tb = {paB0, paB1, dB0, dB1};
      bf16x8 a01A = __builtin_bit_cast(bf16x8, ta);
      bf16x8 a01B = __builtin_bit_cast(bf16x8, tb);
      #pragma unroll
      for (int dt = 0; dt < 4; ++dt){
        oaccA[dt] = __builtin_amdgcn_mfma_f32_16x16x32_bf16(a01A, vpre[dt], oaccA[dt], 0, 0, 0);
        oaccB[dt] = __builtin_amdgcn_mfma_f32_16x16x32_bf16(a01B, vpre[dt], oaccB[dt], 0, 0, 0);
      }
    }
    kf0 = nkf0; kf1 = nkf1;
  }

  // softmax normalizer for q = l16 (full row sum across quads)
  rsumA += __shfl_xor(rsumA, 16);
  rsumA += __shfl_xor(rsumA, 32);
  rsumB += __shfl_xor(rsumB, 16);
  rsumB += __shfl_xor(rsumB, 32);
  float irA  = 1.0f / rsumA;
  float irB  = 1.0f / rsumB;
  float irsA = irA * 0.0625f;           // folded 1/NH for attn
  float irsB = irB * 0.0625f;

  // ---- O epilogue ----
  float irqA[4], irqB[4];
  #pragma unroll
  for (int j = 0; j < 4; ++j){
    irqA[j] = __shfl(irA, quad*4 + j);
    irqB[j] = __shfl(irB, quad*4 + j);
  }
  #pragma unroll
  for (int dt = 0; dt < 4; ++dt){
    float* opA = out + ((size_t)(n*LQ + q0 + quad*4))*DM + w*DH + dt*16 + l16;
    opA[0]      = oaccA[dt][0] * irqA[0];
    opA[DM]     = oaccA[dt][1] * irqA[1];
    opA[2*DM]   = oaccA[dt][2] * irqA[2];
    opA[3*DM]   = oaccA[dt][3] * irqA[3];
    float* opB = opA + (size_t)16*DM;
    opB[0]      = oaccB[dt][0] * irqB[0];
    opB[DM]     = oaccB[dt][1] * irqB[1];
    opB[2*DM]   = oaccB[dt][2] * irqB[2];
    opB[3*DM]   = oaccB[dt][3] * irqB[3];
  }

  // ---- loop2 v2: 8 chunks x (stage 2 wins -> barrier -> reduce -> barrier) --
  for (int ch = 0; ch < 8; ++ch){
    #pragma unroll
    for (int wc = 0; wc < 2; ++wc){
      int win = ch*2 + wc;
      bf16x8 kw[4][2];
      #pragma unroll
      for (int sub = 0; sub < 4; ++sub){
        const short* kp = kb + (size_t)(win*64 + sub*16)*DH;
        kw[sub][0] = *(const bf16x8*)kp;
        kw[sub][1] = *(const bf16x8*)(kp + 32);
      }
      #pragma unroll
      for (int sub = 0; sub < 4; ++sub){
        f32x4 stA = vzero, stB = vzero;
        stA = __builtin_amdgcn_mfma_f32_16x16x32_bf16(kw[sub][0], qfA0, stA, 0, 0, 0);
        stA = __builtin_amdgcn_mfma_f32_16x16x32_bf16(kw[sub][1], qfA1, stA, 0, 0, 0);
        stB = __builtin_amdgcn_mfma_f32_16x16x32_bf16(kw[sub][0], qfB0, stB, 0, 0, 0);
        stB = __builtin_amdgcn_mfma_f32_16x16x32_bf16(kw[sub][1], qfB1, stB, 0, 0, 0);
        float gA0 = __builtin_amdgcn_exp2f(stA[0]*CE) * irsA;
        float gA1 = __builtin_amdgcn_exp2f(stA[1]*CE) * irsA;
        float gA2 = __builtin_amdgcn_exp2f(stA[2]*CE) * irsA;
        float gA3 = __builtin_amdgcn_exp2f(stA[3]*CE) * irsA;
        float gB0 = __builtin_amdgcn_exp2f(stB[0]*CE) * irsB;
        float gB1 = __builtin_amdgcn_exp2f(stB[1]*CE) * irsB;
        float gB2 = __builtin_amdgcn_exp2f(stB[2]*CE) * irsB;
        float gB3 = __builtin_amdgcn_exp2f(stB[3]*CE) * irsB;
        i32x2 wvA = {cvt_pk_bf16(gA0, gA1), cvt_pk_bf16(gA2, gA3)};
        i32x2 wvB = {cvt_pk_bf16(gB0, gB1), cvt_pk_bf16(gB2, gB3)};
        int scol = wc*64 + sub*16 + quad*4;
        *(i32x2*)(&AS2[(w*32 + l16)*RW + scol])      = wvA;
        *(i32x2*)(&AS2[(w*32 + 16 + l16)*RW + scol]) = wvB;
      }
    }
    __syncthreads();
    {
      int ql = tid >> 5;                // 0..31
      int s4 = (tid & 31) << 2;         // 0,4,...,124
      float a0 = 0.f, a1 = 0.f, a2 = 0.f, a3 = 0.f;
      #pragma unroll
      for (int h = 0; h < NH; ++h){
        i32x2 v = *(const i32x2*)(&AS2[(h*32 + ql)*RW + s4]);
        a0 += bf2f((short)(v[0] & 0xffff));
        a1 += bf2f((short)((unsigned)v[0] >> 16));
        a2 += bf2f((short)(v[1] & 0xffff));
        a3 += bf2f((short)((unsigned)v[1] >> 16));
      }
      f32x4 o = {a0, a1, a2, a3};
      *(f32x4*)(&attn[((size_t)(n*LQ + q0 + ql))*LQ + ch*128 + s4]) = o;
    }
    __syncthreads();
  }
}

extern "C" void kernel_launch(void* const* d_in, const int* in_sizes, int n_in,
                              void* d_out, int out_size, void* d_ws, size_t ws_size,
                              hipStream_t stream){
  const float* in = (const float*)d_in[0];
  float* out  = (float*)d_out;
  float* attn = out + (size_t)NB*LQ*DM;
  short* bKw = (short*)d_ws;
  size_t half = (size_t)NB*LQ*DM;          // 8 Mi elements
  short* bTw = bKw + half;

  k0_convert<<<dim3(512), dim3(256),  0, stream>>>(in, bKw, bTw);
  k2_attn   <<<dim3(256), dim3(1024), 0, stream>>>(bKw, bTw, out, attn);
}

// Round 11
// 174.116 us; speedup vs baseline: 1.8613x; 1.4970x over previous
//
#include <hip/hip_runtime.h>

// AttentionLayer: N=8, L=1024, D_MODEL=1024, H=16, d_head=64.
// out  = softmax(QK^T/8)V reshaped   (8,1024,1024) fp32
// attn = mean over heads of softmax  (8,1024,1024) fp32, after out.
//
// Falsified for the 180us k2 plateau: P-LDS chain (R10), prefetch depth
// (R11), L2 bytes (R12), TLP (R14/15), barrier count (R16, reverted).
// R17: per-INSTRUCTION coalescing. R6 made fragment REGIONS contiguous but
//      every hot-loop load is still a 16-segment gather (64 lanes read
//      row(l16)*128B + quad*16B). New lane-ordered packed layouts:
//        bKp[(n,h,fi)][half][lane*8]  : K frag load = one 1KB coalesced instr
//        bVp[(n,vwin,h,dt)][lane*8]   : V frag load = one 1KB coalesced instr
//      loop2 reuses bKp (fi = 4win+sub) with store index s = toff+quad*8+j,
//      toff = (sub>>1)*32 + (sub&1)*4. Q frags (4 loads, once) read fp32 in
//      directly + cvt_pk (RNE, bit-identical). bKw dropped: ws stays 32 MB.
//      Datapath math identical to R13 -> absmax tripwire 0.046875.

#define NB 8
#define LQ 1024
#define DM 1024
#define NH 16
#define DH 64
#define AW 68           // attn stage row stride (shorts)
#define TR 528          // k0 LDS row stride (shorts)

typedef __attribute__((ext_vector_type(4))) float f32x4;
typedef __attribute__((ext_vector_type(8))) short bf16x8;
typedef __attribute__((ext_vector_type(4))) short bf16x4;
typedef __attribute__((ext_vector_type(4))) int   i32x4;
typedef __attribute__((ext_vector_type(2))) int   i32x2;

__device__ inline short f2bf(float f){
  unsigned u = __builtin_bit_cast(unsigned, f);
  u += 0x7fffu + ((u >> 16) & 1u);   // RNE (inputs finite)
  return (short)(u >> 16);
}
__device__ inline float bf2f(short s){
  unsigned u = ((unsigned)(unsigned short)s) << 16;
  return __builtin_bit_cast(float, u);
}
__device__ inline int cvt_pk_bf16(float lo, float hi){
  int r;
  asm("v_cvt_pk_bf16_f32 %0, %1, %2" : "=v"(r) : "v"(lo), "v"(hi));
  return r;
}

// ---------------- k0: fp32 -> bf16 into lane-ordered packed layouts ---------
// block b = (n*32 + win)*2 + dh; 256 threads; LDS tile T[32 s][512 d-local].
__global__ __launch_bounds__(256) void k0_convert(const float* __restrict__ in,
                                                  short* __restrict__ bKp,
                                                  short* __restrict__ bVp){
  __shared__ short T[32*TR];
  int b   = blockIdx.x;
  int dh  = b & 1;                 // d-half: heads dh*8 .. dh*8+7
  int win = (b >> 1) & 31;         // 32-s window == V window index
  int n   = b >> 6;
  int tid = threadIdx.x;

  // step 1: coalesced read + convert + LDS store
  {
    int s  = tid >> 3;             // 0..31
    int c0 = (tid & 7) << 2;
    const float* src = in + ((size_t)(n*LQ + win*32 + s))*DM + dh*512;
    #pragma unroll
    for (int p = 0; p < 16; ++p){
      int c = p*32 + c0;
      f32x4 f = *(const f32x4*)(src + c);
      bf16x4 v = {f2bf(f.x), f2bf(f.y), f2bf(f.z), f2bf(f.w)};
      *(bf16x4*)&T[s*TR + c] = v;
    }
  }
  __syncthreads();

  // step 2: bKp -- frags fi = 2*win + p for heads hl; lane ln holds
  // (row = win*32 + p*4 + perm(ln&15), d = half*32 + (ln>>4)*8 + j)
  // where perm(r) = (r>>2)*8 + (r&3). 16B contiguous src + coalesced dst.
  {
    #pragma unroll
    for (int pass = 0; pass < 8; ++pass){
      int c    = pass*256 + tid;     // 0..2047
      int hl   = c >> 8;             // 0..7
      int p    = (c >> 7) & 1;
      int half = (c >> 6) & 1;
      int ln   = c & 63;
      int l16  = ln & 15;
      int srow = p*4 + ((l16 >> 2) << 3) + (l16 & 3);
      int scol = hl*64 + half*32 + ((ln >> 4) << 3);
      bf16x8 v = *(const bf16x8*)&T[srow*TR + scol];
      size_t dst = ((size_t)((n*NH + dh*8 + hl)*64 + 2*win + p))*1024 + half*512 + ln*8;
      *(bf16x8*)(bKp + dst) = v;
    }
  }

  // step 3: bVp -- V frag (vwin=win, head hl, dt); lane ln holds
  // (d = hl*64 + dt*16 + (ln&15), sl = (ln>>4)*8 + j). transpose gather.
  {
    #pragma unroll
    for (int pass = 0; pass < 8; ++pass){
      int c   = pass*256 + tid;      // 0..2047
      int hl  = c >> 8;              // 0..7
      int dt  = (c >> 6) & 3;
      int ln  = c & 63;
      int col = hl*64 + dt*16 + (ln & 15);
      int sl8 = (ln >> 4) << 3;
      short t0 = T[(sl8+0)*TR + col];
      short t1 = T[(sl8+1)*TR + col];
      short t2 = T[(sl8+2)*TR + col];
      short t3 = T[(sl8+3)*TR + col];
      short t4 = T[(sl8+4)*TR + col];
      short t5 = T[(sl8+5)*TR + col];
      short t6 = T[(sl8+6)*TR + col];
      short t7 = T[(sl8+7)*TR + col];
      bf16x8 v = {t0, t1, t2, t3, t4, t5, t6, t7};
      size_t dst = (((size_t)(n*32 + win)*NH + dh*8 + hl)*4 + dt)*512 + ln*8;
      *(bf16x8*)(bVp + dst) = v;
    }
  }
}

// ---------------- k2: one wave per head, two q-tiles per wave ---------------
// loop1: R10 datapath, all K/V fragment loads now single coalesced instrs.
// loop2: R13 structure, K frags from bKp (fi = 4win+sub), store index
//        compensated by toff.
__global__ __launch_bounds__(1024, 4) void k2_attn(const float* __restrict__ in,
                                                   const short* __restrict__ bKp,
                                                   const short* __restrict__ bVp,
                                                   float* __restrict__ out,
                                                   float* __restrict__ attn){
  __shared__ short AS[2*NH*16*AW];      // 69632 B (loop2 only)
  int tid  = threadIdx.x;
  int lane = tid & 63;
  int w    = tid >> 6;                  // wave id == head id
  int l16  = lane & 15;
  int quad = lane >> 4;
  int n  = blockIdx.x & 7;              // XCD swizzle
  int q0 = (blockIdx.x >> 3) << 5;      // 32 q-rows per block

  const float CE = 0.1803368801111244f; // 0.125 * log2(e)
  const f32x4 vzero = {0.f, 0.f, 0.f, 0.f};

  const short* kpb = bKp + ((size_t)(n*NH + w))*64*1024;  // 64 frags x 1024 shorts

  // Q fragments straight from fp32 input (once per wave; RNE == f2bf)
  const float* qsrc = in + ((size_t)(n*LQ + q0 + l16))*DM + w*DH + quad*8;
  auto ldq = [&](const float* p)->bf16x8 {
    f32x4 a = *(const f32x4*)p;
    f32x4 c = *(const f32x4*)(p + 4);
    i32x4 t = {cvt_pk_bf16(a.x, a.y), cvt_pk_bf16(a.z, a.w),
               cvt_pk_bf16(c.x, c.y), cvt_pk_bf16(c.z, c.w)};
    return __builtin_bit_cast(bf16x8, t);
  };
  bf16x8 qfA0 = ldq(qsrc);
  bf16x8 qfA1 = ldq(qsrc + 32);
  bf16x8 qfB0 = ldq(qsrc + (size_t)16*DM);
  bf16x8 qfB1 = ldq(qsrc + (size_t)16*DM + 32);

  f32x4 oaccA[4], oaccB[4];
  #pragma unroll
  for (int dt = 0; dt < 4; ++dt){ oaccA[dt] = vzero; oaccB[dt] = vzero; }
  float rsumA = 0.f, rsumB = 0.f;

  // ---- loop1: QK + exp (unnormalized) + PV, no barriers, no LDS ----
  bf16x8 kf0 = *(const bf16x8*)(kpb + lane*8);
  bf16x8 kf1 = *(const bf16x8*)(kpb + 512 + lane*8);
  bf16x8 vpre[4];
  int paA0 = 0, paA1 = 0, paB0 = 0, paB1 = 0;
  for (int f = 0; f < 64; ++f){
    const short* nkp = kpb + (size_t)((f + 1) & 63)*1024 + lane*8;
    bf16x8 nkf0 = *(const bf16x8*)nkp;
    bf16x8 nkf1 = *(const bf16x8*)(nkp + 512);
    if ((f & 1) == 0){
      int vwin = f >> 1;
      const short* vb = bVp + (((size_t)(n*32 + vwin)*NH + w)*4)*512 + lane*8;
      #pragma unroll
      for (int dt = 0; dt < 4; ++dt)
        vpre[dt] = *(const bf16x8*)(vb + dt*512);
    }
    f32x4 stA = vzero, stB = vzero;
    stA = __builtin_amdgcn_mfma_f32_16x16x32_bf16(kf0, qfA0, stA, 0, 0, 0);
    stA = __builtin_amdgcn_mfma_f32_16x16x32_bf16(kf1, qfA1, stA, 0, 0, 0);
    stB = __builtin_amdgcn_mfma_f32_16x16x32_bf16(kf0, qfB0, stB, 0, 0, 0);
    stB = __builtin_amdgcn_mfma_f32_16x16x32_bf16(kf1, qfB1, stB, 0, 0, 0);
    float eA0 = __builtin_amdgcn_exp2f(stA[0]*CE);
    float eA1 = __builtin_amdgcn_exp2f(stA[1]*CE);
    float eA2 = __builtin_amdgcn_exp2f(stA[2]*CE);
    float eA3 = __builtin_amdgcn_exp2f(stA[3]*CE);
    float eB0 = __builtin_amdgcn_exp2f(stB[0]*CE);
    float eB1 = __builtin_amdgcn_exp2f(stB[1]*CE);
    float eB2 = __builtin_amdgcn_exp2f(stB[2]*CE);
    float eB3 = __builtin_amdgcn_exp2f(stB[3]*CE);
    rsumA += (eA0 + eA1) + (eA2 + eA3);
    rsumB += (eB0 + eB1) + (eB2 + eB3);
    int dA0 = cvt_pk_bf16(eA0, eA1), dA1 = cvt_pk_bf16(eA2, eA3);
    int dB0 = cvt_pk_bf16(eB0, eB1), dB1 = cvt_pk_bf16(eB2, eB3);
    if ((f & 1) == 0){
      paA0 = dA0; paA1 = dA1; paB0 = dB0; paB1 = dB1;
    } else {
      i32x4 ta = {paA0, paA1, dA0, dA1};
      i32x4 tb = {paB0, paB1, dB0, dB1};
      bf16x8 a01A = __builtin_bit_cast(bf16x8, ta);
      bf16x8 a01B = __builtin_bit_cast(bf16x8, tb);
      #pragma unroll
      for (int dt = 0; dt < 4; ++dt){
        oaccA[dt] = __builtin_amdgcn_mfma_f32_16x16x32_bf16(a01A, vpre[dt], oaccA[dt], 0, 0, 0);
        oaccB[dt] = __builtin_amdgcn_mfma_f32_16x16x32_bf16(a01B, vpre[dt], oaccB[dt], 0, 0, 0);
      }
    }
    kf0 = nkf0; kf1 = nkf1;
  }

  // softmax normalizer for q = l16 (full row sum across quads)
  rsumA += __shfl_xor(rsumA, 16);
  rsumA += __shfl_xor(rsumA, 32);
  rsumB += __shfl_xor(rsumB, 16);
  rsumB += __shfl_xor(rsumB, 32);
  float irA  = 1.0f / rsumA;
  float irB  = 1.0f / rsumB;
  float irsA = irA * 0.0625f;           // folded 1/NH for attn
  float irsB = irB * 0.0625f;

  // ---- O epilogue ----
  float irqA[4], irqB[4];
  #pragma unroll
  for (int j = 0; j < 4; ++j){
    irqA[j] = __shfl(irA, quad*4 + j);
    irqB[j] = __shfl(irB, quad*4 + j);
  }
  #pragma unroll
  for (int dt = 0; dt < 4; ++dt){
    float* opA = out + ((size_t)(n*LQ + q0 + quad*4))*DM + w*DH + dt*16 + l16;
    opA[0]      = oaccA[dt][0] * irqA[0];
    opA[DM]     = oaccA[dt][1] * irqA[1];
    opA[2*DM]   = oaccA[dt][2] * irqA[2];
    opA[3*DM]   = oaccA[dt][3] * irqA[3];
    float* opB = opA + (size_t)16*DM;
    opB[0]      = oaccB[dt][0] * irqB[0];
    opB[DM]     = oaccB[dt][1] * irqB[1];
    opB[2*DM]   = oaccB[dt][2] * irqB[2];
    opB[3*DM]   = oaccB[dt][3] * irqB[3];
  }

  // ---- loop2: recompute QK per 64-s window from bKp, stage, reduce ----
  short* AmineA = &AS[w*16*AW];
  short* AmineB = &AS[NH*16*AW + w*16*AW];
  for (int win = 0; win < 16; ++win){
    bf16x8 kw[4][2];
    #pragma unroll
    for (int sub = 0; sub < 4; ++sub){
      const short* kp = kpb + (size_t)(4*win + sub)*1024 + lane*8;
      kw[sub][0] = *(const bf16x8*)kp;
      kw[sub][1] = *(const bf16x8*)(kp + 512);
    }
    #pragma unroll
    for (int sub = 0; sub < 4; ++sub){
      f32x4 stA = vzero, stB = vzero;
      stA = __builtin_amdgcn_mfma_f32_16x16x32_bf16(kw[sub][0], qfA0, stA, 0, 0, 0);
      stA = __builtin_amdgcn_mfma_f32_16x16x32_bf16(kw[sub][1], qfA1, stA, 0, 0, 0);
      stB = __builtin_amdgcn_mfma_f32_16x16x32_bf16(kw[sub][0], qfB0, stB, 0, 0, 0);
      stB = __builtin_amdgcn_mfma_f32_16x16x32_bf16(kw[sub][1], qfB1, stB, 0, 0, 0);
      float gA0 = __builtin_amdgcn_exp2f(stA[0]*CE) * irsA;
      float gA1 = __builtin_amdgcn_exp2f(stA[1]*CE) * irsA;
      float gA2 = __builtin_amdgcn_exp2f(stA[2]*CE) * irsA;
      float gA3 = __builtin_amdgcn_exp2f(stA[3]*CE) * irsA;
      float gB0 = __builtin_amdgcn_exp2f(stB[0]*CE) * irsB;
      float gB1 = __builtin_amdgcn_exp2f(stB[1]*CE) * irsB;
      float gB2 = __builtin_amdgcn_exp2f(stB[2]*CE) * irsB;
      float gB3 = __builtin_amdgcn_exp2f(stB[3]*CE) * irsB;
      i32x2 wvA = {cvt_pk_bf16(gA0, gA1), cvt_pk_bf16(gA2, gA3)};
      i32x2 wvB = {cvt_pk_bf16(gB0, gB1), cvt_pk_bf16(gB2, gB3)};
      // permuted frag: st[j] is s = toff + quad*8 + j within the window
      int toff = ((sub >> 1) << 5) + ((sub & 1) << 2);
      *(i32x2*)(&AmineA[l16*AW + toff + quad*8]) = wvA;
      *(i32x2*)(&AmineB[l16*AW + toff + quad*8]) = wvB;
    }
    __syncthreads();
    {
      int qr = tid >> 6;                // 0..15
      int s  = tid & 63;                // 0..63
      float sum0 = 0.f, sum1 = 0.f;
      #pragma unroll
      for (int ww = 0; ww < NH; ++ww){
        sum0 += bf2f(AS[ww*16*AW + qr*AW + s]);
        sum1 += bf2f(AS[NH*16*AW + ww*16*AW + qr*AW + s]);
      }
      attn[((size_t)(n*LQ + q0 + qr))*LQ + win*64 + s]      = sum0;
      attn[((size_t)(n*LQ + q0 + 16 + qr))*LQ + win*64 + s] = sum1;
    }
    __syncthreads();
  }
}

extern "C" void kernel_launch(void* const* d_in, const int* in_sizes, int n_in,
                              void* d_out, int out_size, void* d_ws, size_t ws_size,
                              hipStream_t stream){
  const float* in = (const float*)d_in[0];
  float* out  = (float*)d_out;
  float* attn = out + (size_t)NB*LQ*DM;
  short* bKp = (short*)d_ws;
  size_t half = (size_t)NB*LQ*DM;          // 8 Mi elements
  short* bVp = bKp + half;

  k0_convert<<<dim3(512), dim3(256),  0, stream>>>(in, bKp, bVp);
  k2_attn   <<<dim3(256), dim3(1024), 0, stream>>>(in, bKp, bVp, out, attn);
}